// Round 7
// baseline (119.501 us; speedup 1.0000x reference)
//
#include <hip/hip_runtime.h>
#include <hip/hip_bf16.h>
#include <math.h>

#define Bn   4
#define CIN  128
#define Hh   64
#define Ww   64
#define HW   4096
#define CMID 64
#define KOC  100      // (scale*k_up)^2
#define H2   128
#define W2d  128
#define HW2  16384
#define KUP  5
#define BN_EPS 1e-5f
#define CCH  8        // channels per carafe thread (16 chunks of 8)
#define LDP  136      // padded row length (ushorts): 272B, 16B-aligned, breaks
                      // the stride-256B all-lanes-one-bank pattern (G4)

typedef __attribute__((ext_vector_type(4)))  short  short4v;
typedef __attribute__((ext_vector_type(8)))  short  short8v;
typedef __attribute__((ext_vector_type(16))) float  float16v;

__device__ __forceinline__ ushort f2bf(float v) {
    __hip_bfloat16 h = __float2bfloat16(v);
    return *(ushort*)&h;
}
__device__ __forceinline__ float bfbits2f(ushort u) {
    unsigned x = ((unsigned)u) << 16;
    return __uint_as_float(x);
}

// ---------------- Kernel A (v4): 1x1 conv via MFMA with hi/lo bf16 split.
// W1[64co x 4096pix] = cw[64x128] @ X[128x4096] per batch, fp32-accurate:
// x = hi + lo (bf16 pair); dot = hi*wh + hi*wl + lo*wh (lo*wl ~ 2^-18, dropped).
// block = (b, 64-pix tile) -> 256 blocks. LDS: As/Xs hi+lo, [64][136] each.
// Wave = one 32co x 32pix output tile, K=128 (8 chunks x 3 terms = 24 MFMA).
// Operand/epilogue layout identical to the verified enc pattern.
// Piggyback A-prep: 288 elems/block (256*288 = 73728 = 9*128*64).
__global__ __launch_bounds__(256) void comp_kernel(
    const float* __restrict__ X,
    const float* __restrict__ cw,
    const float* __restrict__ cg,
    const float* __restrict__ cb,
    const float* __restrict__ ew,
    ushort* __restrict__ W1b,       // [b][pix][64] bf16
    ushort* __restrict__ Abf)       // [9][128][64]
{
    extern __shared__ __align__(16) char dsm[];
    ushort* AsH = (ushort*)dsm;                  // [64 co][136]
    ushort* AsL = AsH + 64 * LDP;
    ushort* XsH = AsL + 64 * LDP;                // [64 pix][136]
    ushort* XsL = XsH + 64 * LDP;

    int tid  = threadIdx.x;
    int blk  = blockIdx.x;               // 256: b = blk>>6, tile = blk&63
    int b    = blk >> 6;
    int pix0 = (blk & 63) * 64;

    // A-prep: elems [blk*288, +288)
    for (int t = tid; t < 288; t += 256) {
        int i   = blk * 288 + t;
        int cm  = i & 63;
        int kop = (i >> 6) & 127;
        int tap = i >> 13;
        float v = (kop < KOC) ? ew[((size_t)(kop * CMID + cm)) * 9 + tap] : 0.f;
        Abf[i] = f2bf(v);
    }
    // stage cw hi/lo: [co][ci], coalesced read, conflict-free row write
    for (int i = tid; i < 8192; i += 256) {
        int co = i >> 7, ci = i & 127;
        float x  = cw[i];
        ushort h = f2bf(x);
        ushort l = f2bf(x - bfbits2f(h));
        AsH[co * LDP + ci] = h;
        AsL[co * LDP + ci] = l;
    }
    // stage X hi/lo transposed: [pix][ci] (coalesced read; ~8-way LDS write ok)
    const float* xb = X + (size_t)b * CIN * HW + pix0;
    for (int i = tid; i < 8192; i += 256) {
        int p = i & 63, ci = i >> 6;
        float x  = xb[(size_t)ci * HW + p];
        ushort h = f2bf(x);
        ushort l = f2bf(x - bfbits2f(h));
        XsH[p * LDP + ci] = h;
        XsL[p * LDP + ci] = l;
    }
    __syncthreads();

    int lane = tid & 63;
    int wid  = tid >> 6;
    int n    = lane & 31;
    int q    = lane >> 5;                // k-half selector
    int h2   = wid >> 1;                 // co half
    int p2   = wid & 1;                  // pix half

    float16v acc;
#pragma unroll
    for (int i = 0; i < 16; ++i) acc[i] = 0.f;

    const ushort* aH = AsH + (h2 * 32 + n) * LDP + q * 8;
    const ushort* aL = AsL + (h2 * 32 + n) * LDP + q * 8;
    const ushort* xH = XsH + (p2 * 32 + n) * LDP + q * 8;
    const ushort* xL = XsL + (p2 * 32 + n) * LDP + q * 8;

#pragma unroll
    for (int c = 0; c < 8; ++c) {
        short8v ah = *(const short8v*)(aH + c * 16);
        short8v al = *(const short8v*)(aL + c * 16);
        short8v bh = *(const short8v*)(xH + c * 16);
        short8v bl = *(const short8v*)(xL + c * 16);
        acc = __builtin_amdgcn_mfma_f32_32x32x16_bf16(ah, bh, acc, 0, 0, 0);
        acc = __builtin_amdgcn_mfma_f32_32x32x16_bf16(ah, bl, acc, 0, 0, 0);
        acc = __builtin_amdgcn_mfma_f32_32x32x16_bf16(al, bh, acc, 0, 0, 0);
    }

    // epilogue: D col = lane&31 = pix, row = (reg&3)+8*(reg>>2)+4q = co-in-32
    float inv_s = rsqrtf(1.0f + BN_EPS);
    int pixa = pix0 + p2 * 32 + n;
    ushort* wp = W1b + ((size_t)b * HW + pixa) * 64;
#pragma unroll
    for (int g = 0; g < 4; ++g) {
        int base = h2 * 32 + 8 * g + 4 * q;          // co base, always < 64
        float4 gg = *(const float4*)(cg + base);
        float4 bb = *(const float4*)(cb + base);
        float v0 = acc[4*g+0] * (gg.x * inv_s) + bb.x;
        float v1 = acc[4*g+1] * (gg.y * inv_s) + bb.y;
        float v2 = acc[4*g+2] * (gg.z * inv_s) + bb.z;
        float v3 = acc[4*g+3] * (gg.w * inv_s) + bb.w;
        v0 = v0 / (1.f + expf(-v0));
        v1 = v1 / (1.f + expf(-v1));
        v2 = v2 / (1.f + expf(-v2));
        v3 = v3 / (1.f + expf(-v3));
        short4v pk;
        pk[0] = (short)f2bf(v0); pk[1] = (short)f2bf(v1);
        pk[2] = (short)f2bf(v2); pk[3] = (short)f2bf(v3);
        *(short4v*)(wp + base) = pk;                 // 8B store, aligned
    }
}

// ---------------- Kernel B: 3x3 conv as implicit GEMM via MFMA bf16
// (verified round-2 version, unchanged)
// FUSED EPILOGUE: BN + 4-way sub-softmax over k (softmax is PER SUBPIXEL:
// ko mod 4 selects the subpixel; each thread's reg j=reg&3 is exactly one sub).
__global__ __launch_bounds__(256) void enc_kernel(
    const ushort* __restrict__ W1b_us,   // [b][pix][64] bf16
    const ushort* __restrict__ Abf,      // [9][128][64] bf16
    const float* __restrict__ eg,
    const float* __restrict__ eb,
    float* __restrict__ Wsm)             // [b][100][4096] fp32 softmax weights
{
    __shared__ ushort Bs[3 * 34 * 72];   // 14688 B
    __shared__ float  redm[4][8][32];    // per-sub cross-wave max
    __shared__ float  reds[4][8][32];    // per-sub cross-wave sum

    int bid   = blockIdx.x;              // b*128 + h*2 + whalf -> 512 blocks
    int whalf = bid & 1;
    int h     = (bid >> 1) & 63;
    int b     = bid >> 7;
    int w0    = whalf * 32;
    int tid   = threadIdx.x;

    // stage B tile (bf16-pair granularity, coalesced in cm)
    const unsigned* src  = (const unsigned*)W1b_us;  // [b][pix][32] u32 pairs
    unsigned*       dstu = (unsigned*)Bs;            // w-slot stride 36 uints
    for (int i = tid; i < 3 * 34 * 32; i += 256) {
        int cp = i & 31;
        int t  = i >> 5;
        int wl = t % 34;
        int r  = t / 34;
        int gr = h - 1 + r, gw = w0 - 1 + wl;
        unsigned val = 0u;
        if ((unsigned)gr < 64u && (unsigned)gw < 64u)
            val = src[((size_t)b * HW + gr * 64 + gw) * 32 + cp];
        dstu[(r * 34 + wl) * 36 + cp] = val;
    }
    __syncthreads();

    int lane = tid & 63;
    int wid  = tid >> 6;                 // M-tile: ko base = wid*32
    int n    = lane & 31;
    int q    = lane >> 5;                // 0/1 -> k half

    float16v acc;
#pragma unroll
    for (int i = 0; i < 16; ++i) acc[i] = 0.f;

    const ushort* Arow = Abf + ((size_t)(wid * 32 + n)) * 64 + q * 8;

#pragma unroll
    for (int tap = 0; tap < 9; ++tap) {
        int dy = tap / 3, dx = tap % 3;
        int bbase = ((dy * 34) + n + dx) * 72 + q * 8;     // ushort idx, 16B aligned
        const ushort* Atap = Arow + (size_t)tap * 128 * 64;
#pragma unroll
        for (int c = 0; c < 4; ++c) {
            short8v a = *(const short8v*)(Atap + c * 16);
            short8v bf = *(const short8v*)(Bs + bbase + c * 16);
            acc = __builtin_amdgcn_mfma_f32_32x32x16_bf16(a, bf, acc, 0, 0, 0);
        }
    }

    // ---- fused BN + per-subpixel softmax ----
    // reg = 4g+j -> row = j + 8g + 4q -> ko = wid*32 + 8g + 4q + j; ko mod 4 = j.
    float inv_s = rsqrtf(1.0f + BN_EPS);
    int   widq  = wid * 2 + q;

    float v[16];
    float pmax[4] = {-1e30f, -1e30f, -1e30f, -1e30f};
#pragma unroll
    for (int g = 0; g < 4; ++g) {
        int base = wid * 32 + 8 * g + 4 * q;
        if (base < KOC) {
            float4 gg = *(const float4*)(eg + base);
            float4 bb = *(const float4*)(eb + base);
            float v0 = acc[4*g+0] * (gg.x * inv_s) + bb.x;
            float v1 = acc[4*g+1] * (gg.y * inv_s) + bb.y;
            float v2 = acc[4*g+2] * (gg.z * inv_s) + bb.z;
            float v3 = acc[4*g+3] * (gg.w * inv_s) + bb.w;
            v[4*g+0] = v0; v[4*g+1] = v1; v[4*g+2] = v2; v[4*g+3] = v3;
            pmax[0] = fmaxf(pmax[0], v0);
            pmax[1] = fmaxf(pmax[1], v1);
            pmax[2] = fmaxf(pmax[2], v2);
            pmax[3] = fmaxf(pmax[3], v3);
        } else {
            v[4*g+0] = -1e30f; v[4*g+1] = -1e30f;
            v[4*g+2] = -1e30f; v[4*g+3] = -1e30f;
        }
    }

#pragma unroll
    for (int j = 0; j < 4; ++j) redm[j][widq][n] = pmax[j];
    __syncthreads();
    float m[4];
#pragma unroll
    for (int j = 0; j < 4; ++j) {
        float mm = redm[j][0][n];
#pragma unroll
        for (int i = 1; i < 8; ++i) mm = fmaxf(mm, redm[j][i][n]);
        m[j] = mm;
    }

    float psum[4] = {0.f, 0.f, 0.f, 0.f};
#pragma unroll
    for (int g = 0; g < 4; ++g) {
#pragma unroll
        for (int j = 0; j < 4; ++j) {
            float e = expf(v[4*g+j] - m[j]);   // padded rows: exp(-huge) -> 0
            v[4*g+j] = e;
            psum[j] += e;
        }
    }
#pragma unroll
    for (int j = 0; j < 4; ++j) reds[j][widq][n] = psum[j];
    __syncthreads();
    float inv[4];
#pragma unroll
    for (int j = 0; j < 4; ++j) {
        float ss = reds[j][0][n];
#pragma unroll
        for (int i = 1; i < 8; ++i) ss += reds[j][i][n];
        inv[j] = 1.f / ss;
    }

    int pixn = h * 64 + w0 + n;
    float* Wp = Wsm + (size_t)b * KOC * HW + pixn;
#pragma unroll
    for (int reg = 0; reg < 16; ++reg) {
        int row = (reg & 3) + 8 * (reg >> 2) + 4 * q;
        int ko  = wid * 32 + row;
        if (ko < KOC) Wp[(size_t)ko * HW] = v[reg] * inv[reg & 3];
    }
}

// ---------------- Kernel D: CARAFE reassembly (verified round-0 version)
// (parity fold: floor((h2-4+2*ki)/2) = h + ki - 2 for both parities of h2)
__global__ __launch_bounds__(256) void carafe_kernel(
    const float* __restrict__ X,
    const float* __restrict__ Wsm,
    float* __restrict__ out)
{
    int gt = blockIdx.x * blockDim.x + threadIdx.x;    // (chunk*Bn + b)*HW + h*64 + w
    int w  = gt & 63;
    int h  = (gt >> 6) & 63;
    int b  = (gt >> 12) & 3;
    int chunk = gt >> 14;                              // 0..15
    int c0 = chunk * CCH;
    int pix = h * Ww + w;

    float wt[100];
    const float* wpb = Wsm + (size_t)b * KOC * HW + pix;
#pragma unroll
    for (int k = 0; k < 25; ++k) {
        wt[k]      = wpb[(size_t)(4 * k + 0) * HW];
        wt[25 + k] = wpb[(size_t)(4 * k + 1) * HW];
        wt[50 + k] = wpb[(size_t)(4 * k + 2) * HW];
        wt[75 + k] = wpb[(size_t)(4 * k + 3) * HW];
    }

    int off[25];
#pragma unroll
    for (int ki = 0; ki < 5; ++ki) {
#pragma unroll
        for (int kj = 0; kj < 5; ++kj) {
            int k = ki * 5 + kj;
            int r = h + ki - 2, cc = w + kj - 2;
            bool valid = ((unsigned)r < 64u) && ((unsigned)cc < 64u);
            int rc = r < 0 ? 0 : (r > 63 ? 63 : r);
            int cx = cc < 0 ? 0 : (cc > 63 ? 63 : cc);
            off[k] = rc * Ww + cx;
            if (!valid) { wt[k] = 0.f; wt[25+k] = 0.f; wt[50+k] = 0.f; wt[75+k] = 0.f; }
        }
    }

    const float* xp = X + ((size_t)b * CIN + c0) * HW;
    float* o0 = out + ((size_t)b * CIN + c0) * HW2 + (2 * h) * W2d + 2 * w;

    for (int c = 0; c < CCH; ++c) {
        float x[25];
#pragma unroll
        for (int k = 0; k < 25; ++k) x[k] = xp[off[k]];
        float a0 = 0.f, a1 = 0.f, a2 = 0.f, a3 = 0.f;
#pragma unroll
        for (int k = 0; k < 25; ++k) {
            float xv = x[k];
            a0 += wt[k]      * xv;
            a1 += wt[25 + k] * xv;
            a2 += wt[50 + k] * xv;
            a3 += wt[75 + k] * xv;
        }
        *(float2*)o0          = make_float2(a0, a1);
        *(float2*)(o0 + W2d)  = make_float2(a2, a3);
        xp += HW;
        o0 += HW2;
    }
}

extern "C" void kernel_launch(void* const* d_in, const int* in_sizes, int n_in,
                              void* d_out, int out_size, void* d_ws, size_t ws_size,
                              hipStream_t stream)
{
    const float* X  = (const float*)d_in[0];
    const float* cw = (const float*)d_in[1];
    const float* cg = (const float*)d_in[2];
    const float* cb = (const float*)d_in[3];
    const float* ew = (const float*)d_in[4];
    const float* eg = (const float*)d_in[5];
    const float* eb = (const float*)d_in[6];
    float* out = (float*)d_out;

    char* ws = (char*)d_ws;
    ushort* W1b = (ushort*)ws;                            // 4*4096*64 bf16 = 2 MB
    ushort* Abf = (ushort*)(ws + 2097152);                // 9*128*64 = 147456 B
    float*  Wsm = (float*)(ws + 2097152 + 147456);        // 6.55 MB

    comp_kernel  <<<256, 256, 4 * 64 * LDP * 2, stream>>>(X, cw, cg, cb, ew, W1b, Abf);
    enc_kernel   <<<512, 256, 0, stream>>>(W1b, Abf, eg, eb, Wsm);
    carafe_kernel<<<16 * Bn * HW / 256, 256, 0, stream>>>(X, Wsm, out);
}

// Round 8
// 116.929 us; speedup vs baseline: 1.0220x; 1.0220x over previous
//
#include <hip/hip_runtime.h>
#include <hip/hip_bf16.h>
#include <math.h>

#define Bn   4
#define CIN  128
#define Hh   64
#define Ww   64
#define HW   4096
#define CMID 64
#define KOC  100      // (scale*k_up)^2
#define H2   128
#define W2d  128
#define HW2  16384
#define KUP  5
#define BN_EPS 1e-5f
#define CCH  8        // channels per carafe thread (16 chunks of 8)

typedef __attribute__((ext_vector_type(4)))  short  short4v;
typedef __attribute__((ext_vector_type(8)))  short  short8v;
typedef __attribute__((ext_vector_type(4)))  float  float4v;
typedef __attribute__((ext_vector_type(16))) float  float16v;

__device__ __forceinline__ ushort f2bf(float v) {
    __hip_bfloat16 h = __float2bfloat16(v);
    return *(ushort*)&h;
}
__device__ __forceinline__ float bfbits2f(ushort u) {
    unsigned x = ((unsigned)u) << 16;
    return __uint_as_float(x);
}

// ---------------- Kernel A (v5): 1x1 conv via 16x16x32 MFMA, LDS-free.
// Why 16x16: 64co x 4096pix x 4b = 4096 wave-tiles -> 16 waves/CU (4/SIMD),
// vs 32x32's 1024 tiles (1/SIMD, latency-exposed -- r6/r7 both ~30us).
// No LDS, no barrier: A (cw rows) = per-lane float4 loads; B (X cols) =
// stride-HW scalar loads, coalesced across each 16-lane group.
// k-mapping (u,e)->k applied identically to A and B => result exact for any
// true HW k-layout (k-sum is permutation-invariant). C/D layout is the
// HW-verified col=lane&15, row=(lane>>4)*4+reg.
// Accuracy: hi/lo bf16 split (proven in r7): dot = ah*bh + ah*bl + al*bh.
// Piggyback A-prep: 72 elems/block (1024*72 = 73728 = 9*128*64).
__global__ __launch_bounds__(256) void comp_kernel(
    const float* __restrict__ X,
    const float* __restrict__ cw,
    const float* __restrict__ cg,
    const float* __restrict__ cb,
    const float* __restrict__ ew,
    ushort* __restrict__ W1b,       // [b][pix][64] bf16
    ushort* __restrict__ Abf)       // [9][128][64]
{
    int tid = threadIdx.x;
    int bid = blockIdx.x;            // 1024 blocks

    // A-prep: elems [bid*72, +72)
    if (tid < 72) {
        int i   = bid * 72 + tid;
        int cm  = i & 63;
        int kop = (i >> 6) & 127;
        int tap = i >> 13;
        float v = (kop < KOC) ? ew[((size_t)(kop * CMID + cm)) * 9 + tap] : 0.f;
        Abf[i] = f2bf(v);
    }

    int b    = bid >> 8;             // 4 batches
    int rem  = bid & 255;
    int pixG = rem >> 1;             // 128 groups of 32 pix
    int coH  = rem & 1;              // 0/1 -> co half (32)

    int lane = tid & 63;
    int wid  = tid >> 6;             // 4 waves: (co-sub, pix-sub)
    int i16  = lane & 15;
    int u    = lane >> 4;            // 0..3 quarter-wave (k-group)

    int co0  = coH * 32 + (wid >> 1) * 16;
    int pix  = pixG * 32 + (wid & 1) * 16 + i16;

    const float* xcol = X  + (size_t)b * CIN * HW + pix;
    const float* arow = cw + (size_t)(co0 + i16) * CIN;

    float4v acc;
    acc[0] = 0.f; acc[1] = 0.f; acc[2] = 0.f; acc[3] = 0.f;

#pragma unroll
    for (int c = 0; c < 4; ++c) {
        int k0 = c * 32 + u * 8;
        float4 wa0 = *(const float4*)(arow + k0);
        float4 wa1 = *(const float4*)(arow + k0 + 4);
        float wv[8] = {wa0.x, wa0.y, wa0.z, wa0.w, wa1.x, wa1.y, wa1.z, wa1.w};
        float xv[8];
#pragma unroll
        for (int e = 0; e < 8; ++e)
            xv[e] = xcol[(size_t)(k0 + e) * HW];

        short8v ah, al, bh, bl;
#pragma unroll
        for (int e = 0; e < 8; ++e) {
            ushort h = f2bf(wv[e]);
            ah[e] = (short)h;
            al[e] = (short)f2bf(wv[e] - bfbits2f(h));
            ushort xh = f2bf(xv[e]);
            bh[e] = (short)xh;
            bl[e] = (short)f2bf(xv[e] - bfbits2f(xh));
        }
        acc = __builtin_amdgcn_mfma_f32_16x16x32_bf16(ah, bh, acc, 0, 0, 0);
        acc = __builtin_amdgcn_mfma_f32_16x16x32_bf16(ah, bl, acc, 0, 0, 0);
        acc = __builtin_amdgcn_mfma_f32_16x16x32_bf16(al, bh, acc, 0, 0, 0);
    }

    // epilogue: D col = lane&15 = pix, row = u*4 + j = co offset
    float inv_s = rsqrtf(1.0f + BN_EPS);
    int cob = co0 + u * 4;
    float4 gg = *(const float4*)(cg + cob);
    float4 bb = *(const float4*)(cb + cob);
    float v0 = acc[0] * (gg.x * inv_s) + bb.x;
    float v1 = acc[1] * (gg.y * inv_s) + bb.y;
    float v2 = acc[2] * (gg.z * inv_s) + bb.z;
    float v3 = acc[3] * (gg.w * inv_s) + bb.w;
    v0 = v0 / (1.f + expf(-v0));
    v1 = v1 / (1.f + expf(-v1));
    v2 = v2 / (1.f + expf(-v2));
    v3 = v3 / (1.f + expf(-v3));
    short4v pk;
    pk[0] = (short)f2bf(v0); pk[1] = (short)f2bf(v1);
    pk[2] = (short)f2bf(v2); pk[3] = (short)f2bf(v3);
    *(short4v*)(W1b + ((size_t)b * HW + pix) * 64 + cob) = pk;
}

// ---------------- Kernel B: 3x3 conv as implicit GEMM via MFMA bf16
// (verified round-2 version, unchanged)
// FUSED EPILOGUE: BN + 4-way sub-softmax over k (softmax is PER SUBPIXEL:
// ko mod 4 selects the subpixel; each thread's reg j=reg&3 is exactly one sub).
__global__ __launch_bounds__(256) void enc_kernel(
    const ushort* __restrict__ W1b_us,   // [b][pix][64] bf16
    const ushort* __restrict__ Abf,      // [9][128][64] bf16
    const float* __restrict__ eg,
    const float* __restrict__ eb,
    float* __restrict__ Wsm)             // [b][100][4096] fp32 softmax weights
{
    __shared__ ushort Bs[3 * 34 * 72];   // 14688 B
    __shared__ float  redm[4][8][32];    // per-sub cross-wave max
    __shared__ float  reds[4][8][32];    // per-sub cross-wave sum

    int bid   = blockIdx.x;              // b*128 + h*2 + whalf -> 512 blocks
    int whalf = bid & 1;
    int h     = (bid >> 1) & 63;
    int b     = bid >> 7;
    int w0    = whalf * 32;
    int tid   = threadIdx.x;

    // stage B tile (bf16-pair granularity, coalesced in cm)
    const unsigned* src  = (const unsigned*)W1b_us;  // [b][pix][32] u32 pairs
    unsigned*       dstu = (unsigned*)Bs;            // w-slot stride 36 uints
    for (int i = tid; i < 3 * 34 * 32; i += 256) {
        int cp = i & 31;
        int t  = i >> 5;
        int wl = t % 34;
        int r  = t / 34;
        int gr = h - 1 + r, gw = w0 - 1 + wl;
        unsigned val = 0u;
        if ((unsigned)gr < 64u && (unsigned)gw < 64u)
            val = src[((size_t)b * HW + gr * 64 + gw) * 32 + cp];
        dstu[(r * 34 + wl) * 36 + cp] = val;
    }
    __syncthreads();

    int lane = tid & 63;
    int wid  = tid >> 6;                 // M-tile: ko base = wid*32
    int n    = lane & 31;
    int q    = lane >> 5;                // 0/1 -> k half

    float16v acc;
#pragma unroll
    for (int i = 0; i < 16; ++i) acc[i] = 0.f;

    const ushort* Arow = Abf + ((size_t)(wid * 32 + n)) * 64 + q * 8;

#pragma unroll
    for (int tap = 0; tap < 9; ++tap) {
        int dy = tap / 3, dx = tap % 3;
        int bbase = ((dy * 34) + n + dx) * 72 + q * 8;     // ushort idx, 16B aligned
        const ushort* Atap = Arow + (size_t)tap * 128 * 64;
#pragma unroll
        for (int c = 0; c < 4; ++c) {
            short8v a = *(const short8v*)(Atap + c * 16);
            short8v bf = *(const short8v*)(Bs + bbase + c * 16);
            acc = __builtin_amdgcn_mfma_f32_32x32x16_bf16(a, bf, acc, 0, 0, 0);
        }
    }

    // ---- fused BN + per-subpixel softmax ----
    // reg = 4g+j -> row = j + 8g + 4q -> ko = wid*32 + 8g + 4q + j; ko mod 4 = j.
    float inv_s = rsqrtf(1.0f + BN_EPS);
    int   widq  = wid * 2 + q;

    float v[16];
    float pmax[4] = {-1e30f, -1e30f, -1e30f, -1e30f};
#pragma unroll
    for (int g = 0; g < 4; ++g) {
        int base = wid * 32 + 8 * g + 4 * q;
        if (base < KOC) {
            float4 gg = *(const float4*)(eg + base);
            float4 bb = *(const float4*)(eb + base);
            float v0 = acc[4*g+0] * (gg.x * inv_s) + bb.x;
            float v1 = acc[4*g+1] * (gg.y * inv_s) + bb.y;
            float v2 = acc[4*g+2] * (gg.z * inv_s) + bb.z;
            float v3 = acc[4*g+3] * (gg.w * inv_s) + bb.w;
            v[4*g+0] = v0; v[4*g+1] = v1; v[4*g+2] = v2; v[4*g+3] = v3;
            pmax[0] = fmaxf(pmax[0], v0);
            pmax[1] = fmaxf(pmax[1], v1);
            pmax[2] = fmaxf(pmax[2], v2);
            pmax[3] = fmaxf(pmax[3], v3);
        } else {
            v[4*g+0] = -1e30f; v[4*g+1] = -1e30f;
            v[4*g+2] = -1e30f; v[4*g+3] = -1e30f;
        }
    }

#pragma unroll
    for (int j = 0; j < 4; ++j) redm[j][widq][n] = pmax[j];
    __syncthreads();
    float m[4];
#pragma unroll
    for (int j = 0; j < 4; ++j) {
        float mm = redm[j][0][n];
#pragma unroll
        for (int i = 1; i < 8; ++i) mm = fmaxf(mm, redm[j][i][n]);
        m[j] = mm;
    }

    float psum[4] = {0.f, 0.f, 0.f, 0.f};
#pragma unroll
    for (int g = 0; g < 4; ++g) {
#pragma unroll
        for (int j = 0; j < 4; ++j) {
            float e = expf(v[4*g+j] - m[j]);   // padded rows: exp(-huge) -> 0
            v[4*g+j] = e;
            psum[j] += e;
        }
    }
#pragma unroll
    for (int j = 0; j < 4; ++j) reds[j][widq][n] = psum[j];
    __syncthreads();
    float inv[4];
#pragma unroll
    for (int j = 0; j < 4; ++j) {
        float ss = reds[j][0][n];
#pragma unroll
        for (int i = 1; i < 8; ++i) ss += reds[j][i][n];
        inv[j] = 1.f / ss;
    }

    int pixn = h * 64 + w0 + n;
    float* Wp = Wsm + (size_t)b * KOC * HW + pixn;
#pragma unroll
    for (int reg = 0; reg < 16; ++reg) {
        int row = (reg & 3) + 8 * (reg >> 2) + 4 * q;
        int ko  = wid * 32 + row;
        if (ko < KOC) Wp[(size_t)ko * HW] = v[reg] * inv[reg & 3];
    }
}

// ---------------- Kernel D: CARAFE reassembly (verified round-0 version)
// (parity fold: floor((h2-4+2*ki)/2) = h + ki - 2 for both parities of h2)
__global__ __launch_bounds__(256) void carafe_kernel(
    const float* __restrict__ X,
    const float* __restrict__ Wsm,
    float* __restrict__ out)
{
    int gt = blockIdx.x * blockDim.x + threadIdx.x;    // (chunk*Bn + b)*HW + h*64 + w
    int w  = gt & 63;
    int h  = (gt >> 6) & 63;
    int b  = (gt >> 12) & 3;
    int chunk = gt >> 14;                              // 0..15
    int c0 = chunk * CCH;
    int pix = h * Ww + w;

    float wt[100];
    const float* wpb = Wsm + (size_t)b * KOC * HW + pix;
#pragma unroll
    for (int k = 0; k < 25; ++k) {
        wt[k]      = wpb[(size_t)(4 * k + 0) * HW];
        wt[25 + k] = wpb[(size_t)(4 * k + 1) * HW];
        wt[50 + k] = wpb[(size_t)(4 * k + 2) * HW];
        wt[75 + k] = wpb[(size_t)(4 * k + 3) * HW];
    }

    int off[25];
#pragma unroll
    for (int ki = 0; ki < 5; ++ki) {
#pragma unroll
        for (int kj = 0; kj < 5; ++kj) {
            int k = ki * 5 + kj;
            int r = h + ki - 2, cc = w + kj - 2;
            bool valid = ((unsigned)r < 64u) && ((unsigned)cc < 64u);
            int rc = r < 0 ? 0 : (r > 63 ? 63 : r);
            int cx = cc < 0 ? 0 : (cc > 63 ? 63 : cc);
            off[k] = rc * Ww + cx;
            if (!valid) { wt[k] = 0.f; wt[25+k] = 0.f; wt[50+k] = 0.f; wt[75+k] = 0.f; }
        }
    }

    const float* xp = X + ((size_t)b * CIN + c0) * HW;
    float* o0 = out + ((size_t)b * CIN + c0) * HW2 + (2 * h) * W2d + 2 * w;

    for (int c = 0; c < CCH; ++c) {
        float x[25];
#pragma unroll
        for (int k = 0; k < 25; ++k) x[k] = xp[off[k]];
        float a0 = 0.f, a1 = 0.f, a2 = 0.f, a3 = 0.f;
#pragma unroll
        for (int k = 0; k < 25; ++k) {
            float xv = x[k];
            a0 += wt[k]      * xv;
            a1 += wt[25 + k] * xv;
            a2 += wt[50 + k] * xv;
            a3 += wt[75 + k] * xv;
        }
        *(float2*)o0          = make_float2(a0, a1);
        *(float2*)(o0 + W2d)  = make_float2(a2, a3);
        xp += HW;
        o0 += HW2;
    }
}

extern "C" void kernel_launch(void* const* d_in, const int* in_sizes, int n_in,
                              void* d_out, int out_size, void* d_ws, size_t ws_size,
                              hipStream_t stream)
{
    const float* X  = (const float*)d_in[0];
    const float* cw = (const float*)d_in[1];
    const float* cg = (const float*)d_in[2];
    const float* cb = (const float*)d_in[3];
    const float* ew = (const float*)d_in[4];
    const float* eg = (const float*)d_in[5];
    const float* eb = (const float*)d_in[6];
    float* out = (float*)d_out;

    char* ws = (char*)d_ws;
    ushort* W1b = (ushort*)ws;                            // 4*4096*64 bf16 = 2 MB
    ushort* Abf = (ushort*)(ws + 2097152);                // 9*128*64 = 147456 B
    float*  Wsm = (float*)(ws + 2097152 + 147456);        // 6.55 MB

    comp_kernel  <<<1024, 256, 0, stream>>>(X, cw, cg, cb, ew, W1b, Abf);
    enc_kernel   <<<512, 256, 0, stream>>>(W1b, Abf, eg, eb, Wsm);
    carafe_kernel<<<16 * Bn * HW / 256, 256, 0, stream>>>(X, Wsm, out);
}